// Round 1
// baseline (203.618 us; speedup 1.0000x reference)
//
#include <hip/hip_runtime.h>
#include <hip/hip_bf16.h>

constexpr int Nn = 100000;   // nodes
constexpr int Ee = 1600000;  // edges
constexpr int Fd = 128;      // in features
constexpr int Dd = 64;       // out features
constexpr float ALPHA = 0.2f;

constexpr int BSH    = 8;                              // 256 rows per bucket
constexpr int NBUCK  = (Nn + (1 << BSH) - 1) >> BSH;   // 391
constexpr int BSLACK = 8192;                           // slack entries per bucket (mean fill 4096)
constexpr int BCAP   = 16;                             // LDS entries per bucket per edge_bin block
constexpr int BINB   = 1024;                           // edge_bin blocks (1563 edges each, mean fill 4/bucket)
constexpr int HCAP   = 2688;                           // spmm per-half-bucket LDS edge cap (mean 2048, +14 sigma)

typedef __attribute__((ext_vector_type(8))) short bf16x8;   // 8 bf16 (4 VGPRs)
typedef __attribute__((ext_vector_type(4))) float f32x4;    // MFMA accumulator

__device__ __forceinline__ unsigned short f2bf(float f) {  // RTNE
    unsigned int u = __float_as_uint(f);
    u += 0x7fffu + ((u >> 16) & 1u);
    return (unsigned short)(u >> 16);
}
__device__ __forceinline__ float bf2f(unsigned short s) {
    return __uint_as_float((unsigned int)s << 16);
}

// ---------------- MFMA GEMM: h(bf16) = x @ W, ar = h@a_row, ac = h@a_col --------
__global__ __launch_bounds__(256, 4) void gemm_scores(
    const float* __restrict__ x, const float* __restrict__ W,
    const float* __restrict__ a_row, const float* __restrict__ a_col,
    unsigned short* __restrict__ h, float* __restrict__ ar, float* __restrict__ ac)
{
    constexpr int HP = 136;              // LDS pitch (bf16): 2-way bank alias (free)
    __shared__ unsigned short xs[64 * HP];   // x tile, bf16 [node][k]
    __shared__ unsigned short wt[64 * HP];   // W^T,   bf16 [d][k]
    __shared__ float as_[2 * Dd];            // a_row | a_col

    const int tid = threadIdx.x;

    // W staging: float4 loads (8 iterations instead of 32 scalar)
    const float4* wg = (const float4*)W;
    #pragma unroll
    for (int it = 0; it < 8; ++it) {
        int idx4 = tid + 256 * it;           // 0..2047 float4 = 8192 floats
        int k  = idx4 >> 4;                  // row of W (k dim), 16 float4 per row
        int d4 = (idx4 & 15) << 2;           // output-dim offset
        float4 wv = wg[idx4];
        wt[(d4 + 0) * HP + k] = f2bf(wv.x);
        wt[(d4 + 1) * HP + k] = f2bf(wv.y);
        wt[(d4 + 2) * HP + k] = f2bf(wv.z);
        wt[(d4 + 3) * HP + k] = f2bf(wv.w);
    }
    if (tid < 2 * Dd) as_[tid] = (tid < Dd) ? a_row[tid] : a_col[tid - Dd];

    const int node0 = blockIdx.x * 64;
    const float4* xg = (const float4*)(x + (size_t)node0 * Fd);
    #pragma unroll
    for (int it = 0; it < 8; ++it) {
        int g  = tid + 256 * it;
        int nd = g >> 5, k4 = g & 31;
        float4 v = make_float4(0.f, 0.f, 0.f, 0.f);
        if (node0 + nd < Nn) v = xg[g];
        ushort4 bv = make_ushort4(f2bf(v.x), f2bf(v.y), f2bf(v.z), f2bf(v.w));
        *(ushort4*)&xs[nd * HP + k4 * 4] = bv;
    }
    __syncthreads();

    const int lane = tid & 63;
    const int wid  = tid >> 6;
    const int nlo  = lane & 15;
    const int quad = lane >> 4;

    f32x4 acc[4] = {{0.f,0.f,0.f,0.f},{0.f,0.f,0.f,0.f},{0.f,0.f,0.f,0.f},{0.f,0.f,0.f,0.f}};
    const unsigned short* xrow = &xs[(wid * 16 + nlo) * HP + quad * 8];

    #pragma unroll
    for (int ks = 0; ks < 4; ++ks) {
        bf16x8 a = *(const bf16x8*)(xrow + ks * 32);
        #pragma unroll
        for (int t = 0; t < 4; ++t) {
            bf16x8 b = *(const bf16x8*)&wt[(t * 16 + nlo) * HP + quad * 8 + ks * 32];
            acc[t] = __builtin_amdgcn_mfma_f32_16x16x32_bf16(a, b, acc[t], 0, 0, 0);
        }
    }

    #pragma unroll
    for (int r = 0; r < 4; ++r) {
        int node = node0 + wid * 16 + quad * 4 + r;
        float pr = 0.f, pc = 0.f;
        #pragma unroll
        for (int t = 0; t < 4; ++t) {
            float v = acc[t][r];
            pr = fmaf(v, as_[t * 16 + nlo], pr);
            pc = fmaf(v, as_[Dd + t * 16 + nlo], pc);
        }
        #pragma unroll
        for (int o = 1; o < 16; o <<= 1) {
            pr += __shfl_xor(pr, o, 64);
            pc += __shfl_xor(pc, o, 64);
        }
        if (node < Nn) {
            #pragma unroll
            for (int t = 0; t < 4; ++t)
                h[(size_t)node * Dd + t * 16 + nlo] = f2bf(acc[t][r]);
            if (nlo == 0) { ar[node] = pr; ac[node] = pc; }
        }
    }
}

// ---------------- bucket write-pointer init ----------------
__global__ void bwp_init(int* __restrict__ bwp)
{
    int b = blockIdx.x * 256 + threadIdx.x;
    if (b < NBUCK) bwp[b] = b * BSLACK;
}

// ---------------- edge_bin: LDS-binned staging of PACKED 4B edges --------------
// entry = ((r & 255) << 17) | c   (c < 2^17)
__global__ __launch_bounds__(256, 4) void edge_bin(
    const int* __restrict__ rows, const int* __restrict__ cols,
    int* __restrict__ bwp, unsigned int* __restrict__ binned)
{
    __shared__ unsigned int buf[NBUCK * BCAP];   // 25 KB
    __shared__ int lcnt[NBUCK];
    __shared__ int lbase[NBUCK];

    const int tid = threadIdx.x;
    for (int b = tid; b < NBUCK; b += 256) lcnt[b] = 0;
    __syncthreads();

    const int per = (Ee + BINB - 1) / BINB;   // 1563
    const int e0 = blockIdx.x * per;
    const int e1 = min(e0 + per, Ee);

    for (int base = e0; base < e1; base += 256) {
        int e = base + tid;
        if (e < e1) {
            int r = rows[e], c = cols[e];
            int b = r >> BSH;
            unsigned int pe = ((unsigned)(r & 255) << 17) | (unsigned)c;
            int pos = atomicAdd(&lcnt[b], 1);
            if (pos < BCAP) buf[b * BCAP + pos] = pe;
            else {  // rare spill: direct append
                int slot = atomicAdd(&bwp[b], 1);
                if (slot < (b + 1) * BSLACK) binned[slot] = pe;
            }
        }
    }
    __syncthreads();
    for (int b = tid; b < NBUCK; b += 256) {
        int c = min(lcnt[b], BCAP);
        lbase[b] = c ? atomicAdd(&bwp[b], c) : 0;
    }
    __syncthreads();
    // parallel writeout: 8 lanes per bucket, 32 buckets per pass (13 passes)
    for (int b0 = 0; b0 < NBUCK; b0 += 32) {
        int b = b0 + (tid >> 3);
        if (b < NBUCK) {
            int cnt = min(lcnt[b], BCAP);
            int gb = lbase[b];
            for (int i = tid & 7; i < cnt; i += 8)
                binned[gb + i] = buf[b * BCAP + i];
        }
    }
}

// ------------- spmm_fused: in-LDS CSR build + broadcast gather, 8 waves/block -------------
// Block = half-bucket (128 nodes), 512 threads for latency hiding on the h gathers.
__global__ __launch_bounds__(512, 4) void spmm_fused(
    const unsigned int* __restrict__ binned, const int* __restrict__ bwp,
    const float* __restrict__ ar, const float* __restrict__ ac,
    const unsigned short* __restrict__ h, float* __restrict__ out)
{
    __shared__ float2 lce[HCAP];     // 21 KB ordered (col, ex)
    __shared__ int   cnt[128];
    __shared__ int   wp[128];
    __shared__ int   loff[129];
    __shared__ float lar[128];
    __shared__ int   wsh[8];

    const int tid   = threadIdx.x;
    const int b     = blockIdx.x >> 1;
    const int half  = blockIdx.x & 1;
    const int node0 = (b << BSH) + half * 128;
    const int base  = b * BSLACK;
    const int n     = min(bwp[b] - base, BSLACK);

    if (tid < 128) {
        cnt[tid] = 0;
        int node = node0 + tid;
        lar[tid] = (node < Nn) ? ar[node] : 0.f;
    }
    __syncthreads();

    // pass 1: count this half's edges
    for (int s = tid; s < n; s += 512) {
        int rl = (int)(binned[base + s] >> 17) - half * 128;
        if ((unsigned)rl < 128u) atomicAdd(&cnt[rl], 1);
    }
    __syncthreads();

    // exclusive scan (first 128 threads hold counts, rest zero-padded)
    int v = (tid < 128) ? cnt[tid] : 0;
    int lane = tid & 63, w = tid >> 6;
    int incl = v;
    #pragma unroll
    for (int o = 1; o < 64; o <<= 1) {
        int y = __shfl_up(incl, o, 64);
        if (lane >= o) incl += y;
    }
    if (lane == 63) wsh[w] = incl;
    __syncthreads();
    int pre = 0;
    for (int j = 0; j < w; ++j) pre += wsh[j];
    int excl = pre + incl - v;
    if (tid < 128) { loff[tid] = excl; wp[tid] = excl; }
    if (tid == 128) loff[128] = excl;   // total (v=0 here, pre = wsh[0]+wsh[1])
    __syncthreads();

    // pass 2: LeakyReLU+exp, scatter ordered into LDS
    for (int s = tid; s < n; s += 512) {
        unsigned int pe = binned[base + s];
        int rl = (int)(pe >> 17) - half * 128;
        if ((unsigned)rl < 128u) {
            int c = (int)(pe & 0x1FFFFu);
            float sc = lar[rl] + ac[c];
            sc = sc > 0.f ? sc : ALPHA * sc;
            float ex = __expf(sc);
            int pos = atomicAdd(&wp[rl], 1);
            if (pos < HCAP) lce[pos] = make_float2(__int_as_float(c), ex);
        }
    }
    __syncthreads();

    // pass 3: broadcast gather, 32 groups of 16 lanes, 4 nodes per group
    const int grp = tid >> 4, lq = tid & 15;
    const ushort4* h4 = (const ushort4*)h;   // row = 16 ushort4
    #pragma unroll
    for (int i = 0; i < 4; ++i) {
        int rl = grp * 4 + i;
        int node = node0 + rl;
        if (node >= Nn) break;
        int s0 = loff[rl], s1 = loff[rl + 1];
        float4 acc = make_float4(0.f, 0.f, 0.f, 0.f);
        float wsum = 0.f;
        int j = s0;
        for (; j + 8 <= s1; j += 8) {
            float2 p[8];
            ushort4 hv[8];
            #pragma unroll
            for (int u = 0; u < 8; ++u) p[u] = lce[j + u];            // broadcast
            #pragma unroll
            for (int u = 0; u < 8; ++u)
                hv[u] = h4[(size_t)__float_as_int(p[u].x) * 16 + lq]; // 8 in flight
            #pragma unroll
            for (int u = 0; u < 8; ++u) {
                float wgt = p[u].y;
                wsum += wgt;
                acc.x = fmaf(wgt, bf2f(hv[u].x), acc.x);
                acc.y = fmaf(wgt, bf2f(hv[u].y), acc.y);
                acc.z = fmaf(wgt, bf2f(hv[u].z), acc.z);
                acc.w = fmaf(wgt, bf2f(hv[u].w), acc.w);
            }
        }
        for (; j < s1; ++j) {
            float2 p = lce[j];
            float wgt = p.y;
            wsum += wgt;
            ushort4 hv = h4[(size_t)__float_as_int(p.x) * 16 + lq];
            acc.x = fmaf(wgt, bf2f(hv.x), acc.x);
            acc.y = fmaf(wgt, bf2f(hv.y), acc.y);
            acc.z = fmaf(wgt, bf2f(hv.z), acc.z);
            acc.w = fmaf(wgt, bf2f(hv.w), acc.w);
        }
        float inv = (s1 > s0) ? 1.f / wsum : 0.f;
        float4 o = make_float4(acc.x * inv, acc.y * inv, acc.z * inv, acc.w * inv);
        ((float4*)out)[(size_t)node * 16 + lq] = o;
    }
}

// ---------------- launch ----------------
extern "C" void kernel_launch(void* const* d_in, const int* in_sizes, int n_in,
                              void* d_out, int out_size, void* d_ws, size_t ws_size,
                              hipStream_t stream)
{
    const float* x     = (const float*)d_in[0];
    const int*   rows  = (const int*)d_in[1];
    const int*   cols  = (const int*)d_in[2];
    const float* W     = (const float*)d_in[3];
    const float* a_row = (const float*)d_in[4];
    const float* a_col = (const float*)d_in[5];
    float* out = (float*)d_out;

    char* ws = (char*)d_ws;
    size_t o = 0;
    unsigned short* h = (unsigned short*)(ws + o); o += (size_t)Nn * Dd * 2;  // 12.8 MB
    float* ar   = (float*)(ws + o); o += (size_t)Nn * 4;
    float* ac   = (float*)(ws + o); o += (size_t)Nn * 4;
    int*   bwp  = (int*)(ws + o);   o += 512 * 4;
    unsigned int* binned = (unsigned int*)(ws + o); o += (size_t)NBUCK * BSLACK * 4; // 12.8 MB

    bwp_init<<<2, 256, 0, stream>>>(bwp);
    edge_bin<<<BINB, 256, 0, stream>>>(rows, cols, bwp, binned);
    gemm_scores<<<(Nn + 63) / 64, 256, 0, stream>>>(x, W, a_row, a_col, h, ar, ac);
    spmm_fused<<<NBUCK * 2, 512, 0, stream>>>(binned, bwp, ar, ac, h, out);
}

// Round 2
// 183.705 us; speedup vs baseline: 1.1084x; 1.1084x over previous
//
#include <hip/hip_runtime.h>
#include <hip/hip_bf16.h>

constexpr int Nn = 100000;   // nodes
constexpr int Ee = 1600000;  // edges
constexpr int Fd = 128;      // in features
constexpr int Dd = 64;       // out features
constexpr float ALPHA = 0.2f;

constexpr int BSH   = 7;                    // 128 rows per bucket
constexpr int NB    = (Nn + 127) >> 7;      // 782 buckets
constexpr int BSLK  = 4096;                 // slack entries per bucket (mean fill 2048)
constexpr int BINB  = 512;                  // binning blocks (3125 edges each, mean 4/bucket)
constexpr int BCAP  = 10;                   // LDS slots per bucket per bin block
constexpr int GEMB  = (Nn + 63) / 64;       // 1563 gemm blocks
constexpr int HCAP  = 2688;                 // spmm per-bucket LDS edge cap (mean 2048, +14 sigma)
constexpr int HP    = 136;                  // gemm LDS pitch (bf16): 2-way bank alias (free)

typedef __attribute__((ext_vector_type(8))) short bf16x8;   // 8 bf16 (4 VGPRs)
typedef __attribute__((ext_vector_type(4))) float f32x4;    // MFMA accumulator

__device__ __forceinline__ unsigned short f2bf(float f) {  // RTNE
    unsigned int u = __float_as_uint(f);
    u += 0x7fffu + ((u >> 16) & 1u);
    return (unsigned short)(u >> 16);
}
__device__ __forceinline__ float bf2f(unsigned short s) {
    return __uint_as_float((unsigned int)s << 16);
}

// ---------------- bucket write-pointer init ----------------
__global__ void bwp_init(int* __restrict__ bwp)
{
    int b = blockIdx.x * 256 + threadIdx.x;
    if (b < NB) bwp[b] = b * BSLK;
}

// ============ fused bin + gemm: independent phases share one grid ============
// blocks [0, BINB)           : LDS-binned staging of packed 4B edges
//                              entry = ((r & 127) << 17) | c   (c < 2^17)
// blocks [BINB, BINB+GEMB)   : MFMA GEMM h(bf16)=x@W, ar=h@a_row, ac=h@a_col
__global__ __launch_bounds__(256, 4) void bin_gemm(
    const int* __restrict__ rows, const int* __restrict__ cols,
    int* __restrict__ bwp, unsigned int* __restrict__ binned,
    const float* __restrict__ x, const float* __restrict__ W,
    const float* __restrict__ a_row, const float* __restrict__ a_col,
    unsigned short* __restrict__ h, float* __restrict__ ar, float* __restrict__ ac)
{
    __shared__ union {
        struct { unsigned short xs[64 * HP]; unsigned short wt[64 * HP]; float as_[2 * Dd]; } g; // 35.3 KB
        struct { unsigned int buf[NB * BCAP]; int lcnt[NB]; int lbase[NB]; } s;                  // 37.5 KB
    } sm;

    const int tid = threadIdx.x;

    if (blockIdx.x < BINB) {
        // ---------------- binning path ----------------
        for (int b = tid; b < NB; b += 256) sm.s.lcnt[b] = 0;
        __syncthreads();

        const int per = (Ee + BINB - 1) / BINB;   // 3125
        const int e0 = blockIdx.x * per;
        const int e1 = min(e0 + per, Ee);

        for (int base = e0; base < e1; base += 256) {
            int e = base + tid;
            if (e < e1) {
                int r = rows[e], c = cols[e];
                int b = r >> BSH;
                unsigned int pe = ((unsigned)(r & 127) << 17) | (unsigned)c;
                int pos = atomicAdd(&sm.s.lcnt[b], 1);
                if (pos < BCAP) sm.s.buf[b * BCAP + pos] = pe;
                else {  // rare spill (~0.5% of edges): direct append
                    int slot = atomicAdd(&bwp[b], 1);
                    if (slot < (b + 1) * BSLK) binned[slot] = pe;
                }
            }
        }
        __syncthreads();
        for (int b = tid; b < NB; b += 256) {
            int c = min(sm.s.lcnt[b], BCAP);
            sm.s.lbase[b] = c ? atomicAdd(&bwp[b], c) : 0;
        }
        __syncthreads();
        // parallel writeout: 4 lanes per bucket, 64 buckets per pass (13 passes)
        for (int b0 = 0; b0 < NB; b0 += 64) {
            int b = b0 + (tid >> 2);
            if (b < NB) {
                int cnt = min(sm.s.lcnt[b], BCAP);
                int gb = sm.s.lbase[b];
                for (int i = tid & 3; i < cnt; i += 4)
                    binned[gb + i] = sm.s.buf[b * BCAP + i];
            }
        }
    } else {
        // ---------------- gemm path ----------------
        // W staging: float4 loads
        const float4* wg = (const float4*)W;
        #pragma unroll
        for (int it = 0; it < 8; ++it) {
            int idx4 = tid + 256 * it;           // 0..2047 float4 = 8192 floats
            int k  = idx4 >> 4;                  // row of W (k dim), 16 float4 per row
            int d4 = (idx4 & 15) << 2;           // output-dim offset
            float4 wv = wg[idx4];
            sm.g.wt[(d4 + 0) * HP + k] = f2bf(wv.x);
            sm.g.wt[(d4 + 1) * HP + k] = f2bf(wv.y);
            sm.g.wt[(d4 + 2) * HP + k] = f2bf(wv.z);
            sm.g.wt[(d4 + 3) * HP + k] = f2bf(wv.w);
        }
        if (tid < 2 * Dd) sm.g.as_[tid] = (tid < Dd) ? a_row[tid] : a_col[tid - Dd];

        const int node0 = (blockIdx.x - BINB) * 64;
        const float4* xg = (const float4*)(x + (size_t)node0 * Fd);
        #pragma unroll
        for (int it = 0; it < 8; ++it) {
            int g  = tid + 256 * it;
            int nd = g >> 5, k4 = g & 31;
            float4 v = make_float4(0.f, 0.f, 0.f, 0.f);
            if (node0 + nd < Nn) v = xg[g];
            ushort4 bv = make_ushort4(f2bf(v.x), f2bf(v.y), f2bf(v.z), f2bf(v.w));
            *(ushort4*)&sm.g.xs[nd * HP + k4 * 4] = bv;
        }
        __syncthreads();

        const int lane = tid & 63;
        const int wid  = tid >> 6;
        const int nlo  = lane & 15;
        const int quad = lane >> 4;

        f32x4 acc[4] = {{0.f,0.f,0.f,0.f},{0.f,0.f,0.f,0.f},{0.f,0.f,0.f,0.f},{0.f,0.f,0.f,0.f}};
        const unsigned short* xrow = &sm.g.xs[(wid * 16 + nlo) * HP + quad * 8];

        #pragma unroll
        for (int ks = 0; ks < 4; ++ks) {
            bf16x8 a = *(const bf16x8*)(xrow + ks * 32);
            #pragma unroll
            for (int t = 0; t < 4; ++t) {
                bf16x8 b = *(const bf16x8*)&sm.g.wt[(t * 16 + nlo) * HP + quad * 8 + ks * 32];
                acc[t] = __builtin_amdgcn_mfma_f32_16x16x32_bf16(a, b, acc[t], 0, 0, 0);
            }
        }

        #pragma unroll
        for (int r = 0; r < 4; ++r) {
            int node = node0 + wid * 16 + quad * 4 + r;
            float pr = 0.f, pc = 0.f;
            #pragma unroll
            for (int t = 0; t < 4; ++t) {
                float v = acc[t][r];
                pr = fmaf(v, sm.g.as_[t * 16 + nlo], pr);
                pc = fmaf(v, sm.g.as_[Dd + t * 16 + nlo], pc);
            }
            #pragma unroll
            for (int o = 1; o < 16; o <<= 1) {
                pr += __shfl_xor(pr, o, 64);
                pc += __shfl_xor(pc, o, 64);
            }
            if (node < Nn) {
                #pragma unroll
                for (int t = 0; t < 4; ++t)
                    h[(size_t)node * Dd + t * 16 + nlo] = f2bf(acc[t][r]);
                if (nlo == 0) { ar[node] = pr; ac[node] = pc; }
            }
        }
    }
}

// ------------- spmm_fused: in-LDS CSR build + broadcast gather (R0 structure) -------------
// Block = one 128-node bucket; scans ONLY its own entries (no half discard).
__global__ __launch_bounds__(256) void spmm_fused(
    const unsigned int* __restrict__ binned, const int* __restrict__ bwp,
    const float* __restrict__ ar, const float* __restrict__ ac,
    const unsigned short* __restrict__ h, float* __restrict__ out)
{
    __shared__ float2 lce[HCAP];     // 21 KB ordered (col, ex)
    __shared__ int   cnt[128];
    __shared__ int   wp[128];
    __shared__ int   loff[129];
    __shared__ float lar[128];
    __shared__ int   wsh[4];

    const int tid   = threadIdx.x;
    const int b     = blockIdx.x;
    const int node0 = b << BSH;
    const int base  = b * BSLK;
    const int n     = min(bwp[b] - base, BSLK);

    if (tid < 128) {
        cnt[tid] = 0;
        int node = node0 + tid;
        lar[tid] = (node < Nn) ? ar[node] : 0.f;
    }
    __syncthreads();

    // pass 1: count (every entry belongs to this block)
    for (int s = tid; s < n; s += 256)
        atomicAdd(&cnt[binned[base + s] >> 17], 1);
    __syncthreads();

    // exclusive scan (256-wide, top half zero-padded)
    int v = (tid < 128) ? cnt[tid] : 0;
    int lane = tid & 63, w = tid >> 6;
    int incl = v;
    #pragma unroll
    for (int o = 1; o < 64; o <<= 1) {
        int y = __shfl_up(incl, o, 64);
        if (lane >= o) incl += y;
    }
    if (lane == 63) wsh[w] = incl;
    __syncthreads();
    int pre = 0;
    for (int j = 0; j < w; ++j) pre += wsh[j];
    int excl = pre + incl - v;
    if (tid < 128) { loff[tid] = excl; wp[tid] = excl; }
    if (tid == 128) loff[128] = excl;   // total (v=0 here)
    __syncthreads();

    // pass 2: LeakyReLU+exp, scatter ordered into LDS
    for (int s = tid; s < n; s += 256) {
        unsigned int pe = binned[base + s];
        int rl = (int)(pe >> 17);
        int c  = (int)(pe & 0x1FFFFu);
        float sc = lar[rl] + ac[c];
        sc = sc > 0.f ? sc : ALPHA * sc;
        float ex = __expf(sc);
        int pos = atomicAdd(&wp[rl], 1);
        if (pos < HCAP) lce[pos] = make_float2(__int_as_float(c), ex);
    }
    __syncthreads();

    // pass 3: broadcast gather, 16 groups of 16 lanes, 8 nodes per group
    const int grp = tid >> 4, lq = tid & 15;
    const ushort4* h4 = (const ushort4*)h;   // row = 16 ushort4
    #pragma unroll
    for (int i = 0; i < 8; ++i) {
        int rl = grp * 8 + i;
        int node = node0 + rl;
        if (node >= Nn) break;
        int s0 = loff[rl], s1 = loff[rl + 1];
        float4 acc = make_float4(0.f, 0.f, 0.f, 0.f);
        float wsum = 0.f;
        int j = s0;
        for (; j + 8 <= s1; j += 8) {
            float2 p[8];
            ushort4 hv[8];
            #pragma unroll
            for (int u = 0; u < 8; ++u) p[u] = lce[j + u];            // broadcast
            #pragma unroll
            for (int u = 0; u < 8; ++u)
                hv[u] = h4[(size_t)__float_as_int(p[u].x) * 16 + lq]; // 8 in flight
            #pragma unroll
            for (int u = 0; u < 8; ++u) {
                float wgt = p[u].y;
                wsum += wgt;
                acc.x = fmaf(wgt, bf2f(hv[u].x), acc.x);
                acc.y = fmaf(wgt, bf2f(hv[u].y), acc.y);
                acc.z = fmaf(wgt, bf2f(hv[u].z), acc.z);
                acc.w = fmaf(wgt, bf2f(hv[u].w), acc.w);
            }
        }
        for (; j < s1; ++j) {
            float2 p = lce[j];
            float wgt = p.y;
            wsum += wgt;
            ushort4 hv = h4[(size_t)__float_as_int(p.x) * 16 + lq];
            acc.x = fmaf(wgt, bf2f(hv.x), acc.x);
            acc.y = fmaf(wgt, bf2f(hv.y), acc.y);
            acc.z = fmaf(wgt, bf2f(hv.z), acc.z);
            acc.w = fmaf(wgt, bf2f(hv.w), acc.w);
        }
        float inv = (s1 > s0) ? 1.f / wsum : 0.f;
        float4 o = make_float4(acc.x * inv, acc.y * inv, acc.z * inv, acc.w * inv);
        ((float4*)out)[(size_t)node * 16 + lq] = o;
    }
}

// ---------------- launch ----------------
extern "C" void kernel_launch(void* const* d_in, const int* in_sizes, int n_in,
                              void* d_out, int out_size, void* d_ws, size_t ws_size,
                              hipStream_t stream)
{
    const float* x     = (const float*)d_in[0];
    const int*   rows  = (const int*)d_in[1];
    const int*   cols  = (const int*)d_in[2];
    const float* W     = (const float*)d_in[3];
    const float* a_row = (const float*)d_in[4];
    const float* a_col = (const float*)d_in[5];
    float* out = (float*)d_out;

    char* ws = (char*)d_ws;
    size_t o = 0;
    unsigned short* h = (unsigned short*)(ws + o); o += (size_t)Nn * Dd * 2;  // 12.8 MB
    float* ar   = (float*)(ws + o); o += (size_t)Nn * 4;
    float* ac   = (float*)(ws + o); o += (size_t)Nn * 4;
    int*   bwp  = (int*)(ws + o);   o += 1024 * 4;
    unsigned int* binned = (unsigned int*)(ws + o); o += (size_t)NB * BSLK * 4; // 12.8 MB

    bwp_init<<<4, 256, 0, stream>>>(bwp);
    bin_gemm<<<BINB + GEMB, 256, 0, stream>>>(rows, cols, bwp, binned,
                                              x, W, a_row, a_col, h, ar, ac);
    spmm_fused<<<NB, 256, 0, stream>>>(binned, bwp, ar, ac, h, out);
}

// Round 3
// 180.294 us; speedup vs baseline: 1.1294x; 1.0189x over previous
//
#include <hip/hip_runtime.h>
#include <hip/hip_bf16.h>

constexpr int Nn = 100000;   // nodes
constexpr int Ee = 1600000;  // edges
constexpr int Fd = 128;      // in features
constexpr int Dd = 64;       // out features
constexpr float ALPHA = 0.2f;

constexpr int BSH   = 7;                    // 128 rows per bin bucket
constexpr int NB    = (Nn + 127) >> 7;      // 782 buckets
constexpr int BSLK  = 4096;                 // slack entries per bucket (mean fill 2048, +45 sigma)
constexpr int BINB  = 512;                  // binning blocks (3125 edges each, mean 4/bucket)
constexpr int BCAP  = 10;                   // LDS slots per bucket per bin block
constexpr int GEMB  = (Nn + 63) / 64;       // 1563 gemm blocks
constexpr int HCAP  = 1536;                 // spmm per-64-row-block LDS edge cap (mean 1024, +16 sigma)
constexpr int HP    = 136;                  // xs LDS pitch (bf16)
constexpr int HPW   = 138;                  // wt LDS pitch: row stride 276B -> bank step 5 (coprime 32, conflict-free)

typedef __attribute__((ext_vector_type(8))) short bf16x8;   // 8 bf16 (4 VGPRs)
typedef __attribute__((ext_vector_type(4))) float f32x4;    // MFMA accumulator

__device__ __forceinline__ unsigned short f2bf(float f) {  // RTNE
    unsigned int u = __float_as_uint(f);
    u += 0x7fffu + ((u >> 16) & 1u);
    return (unsigned short)(u >> 16);
}
__device__ __forceinline__ float bf2f(unsigned short s) {
    return __uint_as_float((unsigned int)s << 16);
}

// ---------------- bucket write-pointer init ----------------
__global__ void bwp_init(int* __restrict__ bwp)
{
    int b = blockIdx.x * 256 + threadIdx.x;
    if (b < NB) bwp[b] = b * BSLK;
}

// ============ fused bin + gemm: independent phases share one grid ============
// blocks [0, BINB)           : LDS-binned staging of packed 4B edges
//                              entry = ((r & 127) << 17) | c   (c < 2^17)
// blocks [BINB, BINB+GEMB)   : MFMA GEMM h(bf16)=x@W, ar=h@a_row, ac=h@a_col
__global__ __launch_bounds__(256, 4) void bin_gemm(
    const int* __restrict__ rows, const int* __restrict__ cols,
    int* __restrict__ bwp, unsigned int* __restrict__ binned,
    const float* __restrict__ x, const float* __restrict__ W,
    const float* __restrict__ a_row, const float* __restrict__ a_col,
    unsigned short* __restrict__ h, float* __restrict__ ar, float* __restrict__ ac)
{
    __shared__ union {
        struct { unsigned short xs[64 * HP]; unsigned short wt[64 * HPW]; float as_[2 * Dd]; } g; // 35.6 KB
        struct { unsigned int buf[NB * BCAP]; int lcnt[NB]; int lbase[NB]; } s;                   // 37.5 KB
    } sm;

    const int tid = threadIdx.x;

    if (blockIdx.x < BINB) {
        // ---------------- binning path ----------------
        for (int b = tid; b < NB; b += 256) sm.s.lcnt[b] = 0;
        __syncthreads();

        const int per = (Ee + BINB - 1) / BINB;   // 3125
        const int e0 = blockIdx.x * per;
        const int e1 = min(e0 + per, Ee);

        for (int base = e0; base < e1; base += 256) {
            int e = base + tid;
            if (e < e1) {
                int r = rows[e], c = cols[e];
                int b = r >> BSH;
                unsigned int pe = ((unsigned)(r & 127) << 17) | (unsigned)c;
                int pos = atomicAdd(&sm.s.lcnt[b], 1);
                if (pos < BCAP) sm.s.buf[b * BCAP + pos] = pe;
                else {  // rare spill: direct append
                    int slot = atomicAdd(&bwp[b], 1);
                    if (slot < (b + 1) * BSLK) binned[slot] = pe;
                }
            }
        }
        __syncthreads();
        for (int b = tid; b < NB; b += 256) {
            int c = min(sm.s.lcnt[b], BCAP);
            sm.s.lbase[b] = c ? atomicAdd(&bwp[b], c) : 0;
        }
        __syncthreads();
        // parallel writeout: 4 lanes per bucket, 64 buckets per pass (13 passes)
        for (int b0 = 0; b0 < NB; b0 += 64) {
            int b = b0 + (tid >> 2);
            if (b < NB) {
                int cnt = min(sm.s.lcnt[b], BCAP);
                int gb = sm.s.lbase[b];
                for (int i = tid & 3; i < cnt; i += 4)
                    binned[gb + i] = sm.s.buf[b * BCAP + i];
            }
        }
    } else {
        // ---------------- gemm path ----------------
        // W staging: scalar loads, consecutive lanes -> consecutive d rows.
        // wt pitch 138: bank step per row = 69 mod 32 = 5 (coprime) -> conflict-free stores.
        #pragma unroll 4
        for (int it = 0; it < 32; ++it) {
            int idx = tid + 256 * it;
            int k = idx >> 6, d = idx & 63;
            sm.g.wt[d * HPW + k] = f2bf(W[idx]);
        }
        if (tid < 2 * Dd) sm.g.as_[tid] = (tid < Dd) ? a_row[tid] : a_col[tid - Dd];

        const int node0 = (blockIdx.x - BINB) * 64;
        const float4* xg = (const float4*)(x + (size_t)node0 * Fd);
        #pragma unroll
        for (int it = 0; it < 8; ++it) {
            int g  = tid + 256 * it;
            int nd = g >> 5, k4 = g & 31;
            float4 v = make_float4(0.f, 0.f, 0.f, 0.f);
            if (node0 + nd < Nn) v = xg[g];
            ushort4 bv = make_ushort4(f2bf(v.x), f2bf(v.y), f2bf(v.z), f2bf(v.w));
            *(ushort4*)&sm.g.xs[nd * HP + k4 * 4] = bv;
        }
        __syncthreads();

        const int lane = tid & 63;
        const int wid  = tid >> 6;
        const int nlo  = lane & 15;
        const int quad = lane >> 4;

        f32x4 acc[4] = {{0.f,0.f,0.f,0.f},{0.f,0.f,0.f,0.f},{0.f,0.f,0.f,0.f},{0.f,0.f,0.f,0.f}};
        const unsigned short* xrow = &sm.g.xs[(wid * 16 + nlo) * HP + quad * 8];

        #pragma unroll
        for (int ks = 0; ks < 4; ++ks) {
            bf16x8 a = *(const bf16x8*)(xrow + ks * 32);
            #pragma unroll
            for (int t = 0; t < 4; ++t) {
                bf16x8 b = *(const bf16x8*)&sm.g.wt[(t * 16 + nlo) * HPW + quad * 8 + ks * 32];
                acc[t] = __builtin_amdgcn_mfma_f32_16x16x32_bf16(a, b, acc[t], 0, 0, 0);
            }
        }

        #pragma unroll
        for (int r = 0; r < 4; ++r) {
            int node = node0 + wid * 16 + quad * 4 + r;
            float pr = 0.f, pc = 0.f;
            #pragma unroll
            for (int t = 0; t < 4; ++t) {
                float v = acc[t][r];
                pr = fmaf(v, sm.g.as_[t * 16 + nlo], pr);
                pc = fmaf(v, sm.g.as_[Dd + t * 16 + nlo], pc);
            }
            #pragma unroll
            for (int o = 1; o < 16; o <<= 1) {
                pr += __shfl_xor(pr, o, 64);
                pc += __shfl_xor(pc, o, 64);
            }
            if (node < Nn) {
                #pragma unroll
                for (int t = 0; t < 4; ++t)
                    h[(size_t)node * Dd + t * 16 + nlo] = f2bf(acc[t][r]);
                if (nlo == 0) { ar[node] = pr; ac[node] = pc; }
            }
        }
    }
}

// ------------- spmm_fused: 64-row block, register-cached single scan -------------
// Block = 64 output rows (half of a 128-row bin bucket). One global scan of the
// parent bucket into 16 unconditional register slots (full MLP); ac-gather + exp
// computed up front for all slots; wave-0 scan; register scatter; broadcast gather.
__global__ __launch_bounds__(256, 4) void spmm_fused(
    const unsigned int* __restrict__ binned, const int* __restrict__ bwp,
    const float* __restrict__ ar, const float* __restrict__ ac,
    const unsigned short* __restrict__ h, float* __restrict__ out)
{
    __shared__ float2 lce[HCAP];     // 12.3 KB ordered (col, ex)
    __shared__ int   cnt[64];
    __shared__ int   wp[64];
    __shared__ int   loff[65];
    __shared__ float lar[64];

    const int tid   = threadIdx.x;
    const int pb    = blockIdx.x >> 1;          // parent 128-row bucket
    const unsigned half = blockIdx.x & 1;       // which 64-row half
    const int node0 = (pb << BSH) + (int)half * 64;
    const int base  = pb * BSLK;
    const int n     = min(bwp[pb] - base, BSLK);

    if (tid < 64) {
        cnt[tid] = 0;
        int node = node0 + tid;
        lar[tid] = (node < Nn) ? ar[node] : 0.f;
    }
    __syncthreads();

    // pass A: one coalesced scan into registers (loads always in-bounds: s < BSLK)
    unsigned int pe_r[16];
    float av[16];
    float ex_r[16];
    #pragma unroll
    for (int u = 0; u < 16; ++u) {
        int s = (u << 8) + tid;
        unsigned int pe = binned[base + s];
        pe_r[u] = (s < n) ? pe : 0xFFFFFFFFu;   // invalid marker -> rl out of range
    }
    #pragma unroll
    for (int u = 0; u < 16; ++u) {
        int c = (int)(pe_r[u] & 0x1FFFFu);
        av[u] = ac[min(c, Nn - 1)];             // 16 gathers in flight, L2-hot
    }
    #pragma unroll
    for (int u = 0; u < 16; ++u) {
        unsigned int rl = (pe_r[u] >> 17) - half * 64u;
        float sc = lar[rl & 63u] + av[u];
        sc = sc > 0.f ? sc : ALPHA * sc;
        ex_r[u] = __expf(sc);
        if (rl < 64u) atomicAdd(&cnt[rl], 1);
    }
    __syncthreads();

    // wave-0 exclusive scan of 64 counters
    if (tid < 64) {
        int v = cnt[tid];
        int incl = v;
        #pragma unroll
        for (int o = 1; o < 64; o <<= 1) {
            int y = __shfl_up(incl, o, 64);
            if (tid >= o) incl += y;
        }
        loff[tid] = incl - v;
        wp[tid]   = incl - v;
        if (tid == 63) loff[64] = incl;
    }
    __syncthreads();

    // pass B: scatter ordered (col, ex) from registers
    #pragma unroll
    for (int u = 0; u < 16; ++u) {
        unsigned int rl = (pe_r[u] >> 17) - half * 64u;
        if (rl < 64u) {
            int pos = atomicAdd(&wp[rl], 1);
            if (pos < HCAP)
                lce[pos] = make_float2(__int_as_float((int)(pe_r[u] & 0x1FFFFu)), ex_r[u]);
        }
    }
    __syncthreads();

    // pass 3: broadcast gather, 16 groups of 16 lanes, 4 nodes per group
    const int grp = tid >> 4, lq = tid & 15;
    const ushort4* h4 = (const ushort4*)h;   // row = 16 ushort4
    #pragma unroll
    for (int i = 0; i < 4; ++i) {
        int rl = grp * 4 + i;
        int node = node0 + rl;
        if (node >= Nn) break;
        int s0 = loff[rl], s1 = loff[rl + 1];
        float4 acc = make_float4(0.f, 0.f, 0.f, 0.f);
        float wsum = 0.f;
        int j = s0;
        for (; j + 8 <= s1; j += 8) {
            float2 p[8];
            ushort4 hv[8];
            #pragma unroll
            for (int u = 0; u < 8; ++u) p[u] = lce[j + u];            // broadcast
            #pragma unroll
            for (int u = 0; u < 8; ++u)
                hv[u] = h4[(size_t)__float_as_int(p[u].x) * 16 + lq]; // 8 in flight
            #pragma unroll
            for (int u = 0; u < 8; ++u) {
                float wgt = p[u].y;
                wsum += wgt;
                acc.x = fmaf(wgt, bf2f(hv[u].x), acc.x);
                acc.y = fmaf(wgt, bf2f(hv[u].y), acc.y);
                acc.z = fmaf(wgt, bf2f(hv[u].z), acc.z);
                acc.w = fmaf(wgt, bf2f(hv[u].w), acc.w);
            }
        }
        for (; j < s1; ++j) {
            float2 p = lce[j];
            float wgt = p.y;
            wsum += wgt;
            ushort4 hv = h4[(size_t)__float_as_int(p.x) * 16 + lq];
            acc.x = fmaf(wgt, bf2f(hv.x), acc.x);
            acc.y = fmaf(wgt, bf2f(hv.y), acc.y);
            acc.z = fmaf(wgt, bf2f(hv.z), acc.z);
            acc.w = fmaf(wgt, bf2f(hv.w), acc.w);
        }
        float inv = (s1 > s0) ? 1.f / wsum : 0.f;
        float4 o = make_float4(acc.x * inv, acc.y * inv, acc.z * inv, acc.w * inv);
        ((float4*)out)[(size_t)node * 16 + lq] = o;
    }
}

// ---------------- launch ----------------
extern "C" void kernel_launch(void* const* d_in, const int* in_sizes, int n_in,
                              void* d_out, int out_size, void* d_ws, size_t ws_size,
                              hipStream_t stream)
{
    const float* x     = (const float*)d_in[0];
    const int*   rows  = (const int*)d_in[1];
    const int*   cols  = (const int*)d_in[2];
    const float* W     = (const float*)d_in[3];
    const float* a_row = (const float*)d_in[4];
    const float* a_col = (const float*)d_in[5];
    float* out = (float*)d_out;

    char* ws = (char*)d_ws;
    size_t o = 0;
    unsigned short* h = (unsigned short*)(ws + o); o += (size_t)Nn * Dd * 2;  // 12.8 MB
    float* ar   = (float*)(ws + o); o += (size_t)Nn * 4;
    float* ac   = (float*)(ws + o); o += (size_t)Nn * 4;
    int*   bwp  = (int*)(ws + o);   o += 1024 * 4;
    unsigned int* binned = (unsigned int*)(ws + o); o += (size_t)NB * BSLK * 4; // 12.8 MB

    bwp_init<<<4, 256, 0, stream>>>(bwp);
    bin_gemm<<<BINB + GEMB, 256, 0, stream>>>(rows, cols, bwp, binned,
                                              x, W, a_row, a_col, h, ar, ac);
    spmm_fused<<<NB * 2, 256, 0, stream>>>(binned, bwp, ar, ac, h, out);
}